// Round 2
// baseline (91.694 us; speedup 1.0000x reference)
//
#include <hip/hip_runtime.h>

#define DI __device__ __forceinline__

constexpr int BATCH = 256;
constexpr int INF   = 4096;   // in_features
constexpr int NGRP  = 1024;   // INF/4
constexpr int MOUT  = 4096;   // out_features

constexpr int BN     = 64;    // out-cols per block (BM = 256 = full batch)
constexpr int KSPLIT = 16;
constexpr int KRANGE = INF / KSPLIT;  // 256
constexpr int BK     = 64;
constexpr int NIT    = KRANGE / BK;   // 4

using bf16x8 = __attribute__((ext_vector_type(8))) short;
using f32x4  = __attribute__((ext_vector_type(4))) float;

// D4 half-codebook, stored as 2x the actual values (int8); actual = v * 0.5
__device__ __constant__ signed char D4_I8[512] = {
     0, 0, 0, 0,  -4, 0, 0, 0,  -2,-2,-2,-2,  -2,-2,-2, 0,  -2,-2,-2, 2,  -2,-2, 0,-2,  -2,-2, 0, 0,  -2,-2, 0, 2,
    -2,-2, 2,-2,  -2,-2, 2, 0,  -2,-2, 2, 2,  -2, 0,-2,-2,  -2, 0,-2, 0,  -2, 0,-2, 2,  -2, 0, 0,-2,  -2, 0, 0, 0,
    -2, 0, 0, 2,  -2, 0, 2,-2,  -2, 0, 2, 0,  -2, 0, 2, 2,  -2, 2,-2,-2,  -2, 2,-2, 0,  -2, 2,-2, 2,  -2, 2, 0,-2,
    -2, 2, 0, 0,  -2, 2, 0, 2,  -2, 2, 2,-2,  -2, 2, 2, 0,  -2, 2, 2, 2,   0,-4, 0, 0,   0,-2,-2,-2,   0,-2,-2, 0,
     0,-2,-2, 2,   0,-2, 0,-2,   0,-2, 0, 0,   0,-2, 0, 2,   0,-2, 2,-2,   0,-2, 2, 0,   0,-2, 2, 2,   0, 0,-4, 0,
     0, 0,-2,-2,   0, 0,-2, 0,   0, 0,-2, 2,   0, 0, 0,-4,   0, 0, 0,-2,
    -3,-1,-3,-1,  -3,-1,-3, 1,  -3,-1,-1,-3,  -3,-1,-1,-1,  -3,-1,-1, 1,  -3,-1,-1, 3,  -3,-1, 1,-3,  -3,-1, 1,-1,
    -3,-1, 1, 1,  -3,-1, 1, 3,  -3,-1, 3,-1,  -3,-1, 3, 1,  -3, 1,-3,-1,  -3, 1,-3, 1,  -3, 1,-1,-3,  -3, 1,-1,-1,
    -3, 1,-1, 1,  -3, 1,-1, 3,  -3, 1, 1,-3,  -3, 1, 1,-1,  -3, 1, 1, 1,  -3, 1, 1, 3,  -3, 1, 3,-1,  -3, 1, 3, 1,
    -3, 3,-1,-1,  -3, 3, 1,-1,  -3, 3, 1, 1,  -1,-3,-3,-1,  -1,-3,-3, 1,  -1,-3,-1,-3,  -1,-3,-1,-1,  -1,-3,-1, 1,
    -1,-3,-1, 3,  -1,-3, 1,-3,  -1,-3, 1,-1,  -1,-3, 1, 1,  -1,-3, 1, 3,  -1,-3, 3,-1,  -1,-3, 3, 1,  -1,-1,-3,-3,
    -1,-1,-3,-1,  -1,-1,-3, 1,  -1,-1,-3, 3,  -1,-1,-1,-3,  -1,-1,-1,-1,  -1,-1,-1, 1,  -1,-1,-1, 3,  -1,-1, 1,-3,
    -1,-1, 1,-1,  -1,-1, 1, 1,  -1,-1, 1, 3,  -1,-1, 3,-3,  -1,-1, 3,-1,  -1,-1, 3, 1,  -1,-1, 3, 3,  -1, 1,-3,-3,
    -1, 1,-3,-1,  -1, 1,-3, 1,  -1, 1,-3, 3,  -1, 1,-1,-3,  -1, 1,-1,-1,  -1, 1,-1, 1,  -1, 1,-1, 3,  -1, 1, 1,-3,
    -1, 1, 1,-1,  -1, 1, 1, 1,  -1, 1, 1, 3,  -1, 1, 3,-3,  -1, 1, 3,-1,  -1, 1, 3, 1,  -1, 1, 3, 3,  -1, 3,-3,-1,
    -1, 3,-3, 1,  -1, 3,-1,-3,  -1, 3,-1,-1,  -1, 3,-1, 1,  -1, 3,-1, 3,  -1, 3, 1,-3,  -1, 3, 1,-1,  -1, 3, 1, 1,
    -1, 3, 1, 3,  -1, 3, 3,-1,  -1, 3, 3, 1
};

DI unsigned short f2bf(float f) {  // f32 -> bf16 bits, round-to-nearest-even
  unsigned int u = __float_as_uint(f);
  u += 0x7fffu + ((u >> 16) & 1u);
  return (unsigned short)(u >> 16);
}

// Fused: zero d_out + build Xs = input * scaleW_DSC * Qscales (bf16) into d_ws.
__global__ __launch_bounds__(256) void prep_kernel(
    const float* __restrict__ inp, const float* __restrict__ sw,
    const float* __restrict__ qs, unsigned short* __restrict__ xs,
    float* __restrict__ out) {
  int i = blockIdx.x * 256 + threadIdx.x;      // group-of-4 index, 262144 total
  reinterpret_cast<float4*>(out)[i] = make_float4(0.f, 0.f, 0.f, 0.f);
  int g = i & (NGRP - 1);
  float4 v = reinterpret_cast<const float4*>(inp)[i];
  float4 s = reinterpret_cast<const float4*>(sw)[g];
  float  q = qs[g];
  ushort4 o;
  o.x = f2bf(v.x * s.x * q);
  o.y = f2bf(v.y * s.y * q);
  o.z = f2bf(v.z * s.z * q);
  o.w = f2bf(v.w * s.w * q);
  reinterpret_cast<ushort4*>(xs)[i] = o;
}

// Barrier-free fused dequant-GEMM. Each wave owns a 128x32 output tile;
// B-fragments are gathered straight from Qidxs (int2 per frag) and
// dequantized via 2 random ds_read_b64 lookups into a 256-entry signed
// codebook table. A-fragments read direct from L2-resident Xs.
__global__ __launch_bounds__(256, 3) void gemm_kernel(
    const unsigned short* __restrict__ xs, const int* __restrict__ qidx,
    float* __restrict__ out) {
  __shared__ unsigned long long tbl[256];          // 2 KB, sign-folded bf16x4

  const int tid  = threadIdx.x;
  const int lane = tid & 63;
  const int wave = tid >> 6;

  // ---- XCD-aware swizzle: all 16 k-splits of an n-tile on ONE XCD so the
  // split-K atomics RMW in a single L2 (assumes dispatch xcd = wgid % 8).
  const int bid   = blockIdx.x;          // 0..1023
  const int xcd   = bid & 7;
  const int local = bid >> 3;            // 0..127
  const int nt    = xcd + (local & 7) * 8;   // 0..63
  const int ks    = local >> 3;              // 0..15
  const int n0 = nt * BN, k0 = ks * KRANGE;

  // ---- build signed codebook table: tbl[i] = 4 packed bf16, tbl[i+128] = -tbl[i]
  {
    int r = tid & 127, sg = tid >> 7;
    unsigned long long v = 0;
#pragma unroll
    for (int j = 0; j < 4; ++j) {
      float f = (float)D4_I8[r * 4 + j] * 0.5f;
      unsigned int b = __float_as_uint(f) ^ (sg ? 0x80000000u : 0u);
      v |= (unsigned long long)(b >> 16) << (16 * j);
    }
    tbl[tid] = v;
  }
  __syncthreads();          // the only barrier

  // ---- per-lane bases. Wave tile: 128 (m) x 32 (n); waves 2m x 2n.
  const int l15 = lane & 15, l4 = lane >> 4;
  const int wm = wave >> 1, wn = wave & 1;
  const unsigned short* ab = xs + (size_t)(wm * 128 + l15) * INF + k0 + l4 * 8;
  const int* qb = qidx + (size_t)(n0 + wn * 32 + l15) * NGRP + (k0 >> 2) + l4 * 2;

  f32x4 acc[8][2] = {};

#pragma unroll
  for (int t = 0; t < NIT; ++t) {
    // B fragments: gather 2 indices per frag, dequant via table.
    bf16x8 bfr[2][2];
#pragma unroll
    for (int ni = 0; ni < 2; ++ni)
#pragma unroll
      for (int kk = 0; kk < 2; ++kk) {
        int2 q = *reinterpret_cast<const int2*>(
            qb + (size_t)ni * 16 * NGRP + t * 16 + kk * 8);
        union { unsigned long long u[2]; bf16x8 v; } c;
        c.u[0] = tbl[q.x & 255];
        c.u[1] = tbl[q.y & 255];
        bfr[ni][kk] = c.v;
      }
#pragma unroll
    for (int kk = 0; kk < 2; ++kk)
#pragma unroll
      for (int mi = 0; mi < 8; ++mi) {
        bf16x8 a = *reinterpret_cast<const bf16x8*>(
            ab + (size_t)mi * 16 * INF + t * 64 + kk * 32);
#pragma unroll
        for (int ni = 0; ni < 2; ++ni)
          acc[mi][ni] = __builtin_amdgcn_mfma_f32_16x16x32_bf16(
              a, bfr[ni][kk], acc[mi][ni], 0, 0, 0);
      }
  }

  // ---- split-K accumulate (out pre-zeroed by prep_kernel)
  float* ob = out + (size_t)(wm * 128 + l4 * 4) * MOUT + n0 + wn * 32 + l15;
#pragma unroll
  for (int mi = 0; mi < 8; ++mi)
#pragma unroll
    for (int ni = 0; ni < 2; ++ni)
#pragma unroll
      for (int r = 0; r < 4; ++r)
        atomicAdd(ob + (size_t)(mi * 16 + r) * MOUT + ni * 16, acc[mi][ni][r]);
}

extern "C" void kernel_launch(void* const* d_in, const int* in_sizes, int n_in,
                              void* d_out, int out_size, void* d_ws, size_t ws_size,
                              hipStream_t stream) {
  const float* inp = (const float*)d_in[0];
  const float* sw  = (const float*)d_in[1];
  const float* qs  = (const float*)d_in[2];
  const int*   qi  = (const int*)d_in[3];
  float* out = (float*)d_out;
  unsigned short* xs = (unsigned short*)d_ws;   // 256*4096 bf16 = 2 MB scratch

  prep_kernel<<<(BATCH * INF / 4) / 256, 256, 0, stream>>>(inp, sw, qs, xs, out);

  constexpr int GRID = (MOUT / BN) * KSPLIT;   // 64 * 16 = 1024
  gemm_kernel<<<GRID, 256, 0, stream>>>(xs, qi, out);
}

// Round 3
// 41.097 us; speedup vs baseline: 2.2312x; 2.2312x over previous
//
#include <hip/hip_runtime.h>

#define DI __device__ __forceinline__

constexpr int BATCH = 256;
constexpr int INF   = 4096;   // in_features
constexpr int NGRP  = 1024;   // INF/4
constexpr int MOUT  = 4096;   // out_features

constexpr int BM = 64, BN = 64;         // block output tile
constexpr int WK = 512;                 // K-slice per wave (8 waves cover 4096)
constexpr int NSTEP = WK / 32;          // 16 k-steps of 32
constexpr int RP = 68;                  // padded LDS row stride (f32), 16B-aligned

using bf16x8 = __attribute__((ext_vector_type(8))) short;
using f32x4  = __attribute__((ext_vector_type(4))) float;

// D4 half-codebook, stored as 2x the actual values (int8); actual = v * 0.5
__device__ __constant__ signed char D4_I8[512] = {
     0, 0, 0, 0,  -4, 0, 0, 0,  -2,-2,-2,-2,  -2,-2,-2, 0,  -2,-2,-2, 2,  -2,-2, 0,-2,  -2,-2, 0, 0,  -2,-2, 0, 2,
    -2,-2, 2,-2,  -2,-2, 2, 0,  -2,-2, 2, 2,  -2, 0,-2,-2,  -2, 0,-2, 0,  -2, 0,-2, 2,  -2, 0, 0,-2,  -2, 0, 0, 0,
    -2, 0, 0, 2,  -2, 0, 2,-2,  -2, 0, 2, 0,  -2, 0, 2, 2,  -2, 2,-2,-2,  -2, 2,-2, 0,  -2, 2,-2, 2,  -2, 2, 0,-2,
    -2, 2, 0, 0,  -2, 2, 0, 2,  -2, 2, 2,-2,  -2, 2, 2, 0,  -2, 2, 2, 2,   0,-4, 0, 0,   0,-2,-2,-2,   0,-2,-2, 0,
     0,-2,-2, 2,   0,-2, 0,-2,   0,-2, 0, 0,   0,-2, 0, 2,   0,-2, 2,-2,   0,-2, 2, 0,   0,-2, 2, 2,   0, 0,-4, 0,
     0, 0,-2,-2,   0, 0,-2, 0,   0, 0,-2, 2,   0, 0, 0,-4,   0, 0, 0,-2,
    -3,-1,-3,-1,  -3,-1,-3, 1,  -3,-1,-1,-3,  -3,-1,-1,-1,  -3,-1,-1, 1,  -3,-1,-1, 3,  -3,-1, 1,-3,  -3,-1, 1,-1,
    -3,-1, 1, 1,  -3,-1, 1, 3,  -3,-1, 3,-1,  -3,-1, 3, 1,  -3, 1,-3,-1,  -3, 1,-3, 1,  -3, 1,-1,-3,  -3, 1,-1,-1,
    -3, 1,-1, 1,  -3, 1,-1, 3,  -3, 1, 1,-3,  -3, 1, 1,-1,  -3, 1, 1, 1,  -3, 1, 1, 3,  -3, 1, 3,-1,  -3, 1, 3, 1,
    -3, 3,-1,-1,  -3, 3, 1,-1,  -3, 3, 1, 1,  -1,-3,-3,-1,  -1,-3,-3, 1,  -1,-3,-1,-3,  -1,-3,-1,-1,  -1,-3,-1, 1,
    -1,-3,-1, 3,  -1,-3, 1,-3,  -1,-3, 1,-1,  -1,-3, 1, 1,  -1,-3, 1, 3,  -1,-3, 3,-1,  -1,-3, 3, 1,  -1,-1,-3,-3,
    -1,-1,-3,-1,  -1,-1,-3, 1,  -1,-1,-3, 3,  -1,-1,-1,-3,  -1,-1,-1,-1,  -1,-1,-1, 1,  -1,-1,-1, 3,  -1,-1, 1,-3,
    -1,-1, 1,-1,  -1,-1, 1, 1,  -1,-1, 1, 3,  -1,-1, 3,-3,  -1,-1, 3,-1,  -1,-1, 3, 1,  -1,-1, 3, 3,  -1, 1,-3,-3,
    -1, 1,-3,-1,  -1, 1,-3, 1,  -1, 1,-3, 3,  -1, 1,-1,-3,  -1, 1,-1,-1,  -1, 1,-1, 1,  -1, 1,-1, 3,  -1, 1, 1,-3,
    -1, 1, 1,-1,  -1, 1, 1, 1,  -1, 1, 1, 3,  -1, 1, 3,-3,  -1, 1, 3,-1,  -1, 1, 3, 1,  -1, 1, 3, 3,  -1, 3,-3,-1,
    -1, 3,-3, 1,  -1, 3,-1,-3,  -1, 3,-1,-1,  -1, 3,-1, 1,  -1, 3,-1, 3,  -1, 3, 1,-3,  -1, 3, 1,-1,  -1, 3, 1, 1,
    -1, 3, 1, 3,  -1, 3, 3,-1,  -1, 3, 3, 1
};

DI unsigned short f2bf(float f) {  // f32 -> bf16 bits, round-to-nearest-even
  unsigned int u = __float_as_uint(f);
  u += 0x7fffu + ((u >> 16) & 1u);
  return (unsigned short)(u >> 16);
}

// Build Xs = input * scaleW_DSC * Qscales (bf16) into d_ws.
__global__ __launch_bounds__(256) void prep_kernel(
    const float* __restrict__ inp, const float* __restrict__ sw,
    const float* __restrict__ qs, unsigned short* __restrict__ xs) {
  int i = blockIdx.x * 256 + threadIdx.x;      // group-of-4 index, 262144 total
  int g = i & (NGRP - 1);
  float4 v = reinterpret_cast<const float4*>(inp)[i];
  float4 s = reinterpret_cast<const float4*>(sw)[g];
  float  q = qs[g];
  ushort4 o;
  o.x = f2bf(v.x * s.x * q);
  o.y = f2bf(v.y * s.y * q);
  o.z = f2bf(v.z * s.z * q);
  o.w = f2bf(v.w * s.w * q);
  reinterpret_cast<ushort4*>(xs)[i] = o;
}

// Fused dequant-GEMM, block-local split-K.
// Block = 512 thr / 8 waves; block tile 64(m) x 64(n); each wave computes the
// full tile over a disjoint K/8 slice, partials reduced through LDS, output
// written once with plain coalesced stores (no atomics).
__global__ __launch_bounds__(512, 2) void gemm_kernel(
    const unsigned short* __restrict__ xs, const int* __restrict__ qidx,
    float* __restrict__ out) {
  __shared__ unsigned long long tbl[256];   // 2 KB, sign-folded bf16x4 codebook
  __shared__ float red[8][BM * RP];         // 8 x 17.4 KB partial tiles

  const int tid  = threadIdx.x;
  const int lane = tid & 63;
  const int wave = tid >> 6;                // 0..7 = k-slice
  const int l15  = lane & 15, l4 = lane >> 4;

  // ---- XCD swizzle: the 4 m-blocks of one n-tile share an XCD so the 4x
  // Qidxs re-read is an L2 hit (2 MB Qidxs region per XCD).
  const int bid = blockIdx.x;               // 0..255
  const int nt  = (bid & 7) * 8 + ((bid >> 3) & 7);   // 0..63
  const int mt  = bid >> 6;                           // 0..3
  const int m0 = mt * BM, n0 = nt * BN;

  // ---- signed codebook table: tbl[i] = 4 packed bf16, tbl[i+128] = -tbl[i]
  if (tid < 256) {
    int r = tid & 127, sg = tid >> 7;
    unsigned long long v = 0;
#pragma unroll
    for (int j = 0; j < 4; ++j) {
      float f = (float)D4_I8[r * 4 + j] * 0.5f;
      unsigned int b = __float_as_uint(f) ^ (sg ? 0x80000000u : 0u);
      v |= (unsigned long long)(b >> 16) << (16 * j);
    }
    tbl[tid] = v;
  }
  __syncthreads();

  // ---- per-lane bases for this wave's k-slice
  const int k0 = wave * WK;
  const unsigned short* ab = xs + (size_t)(m0 + l15) * INF + k0 + l4 * 8;
  const int* qb = qidx + (size_t)(n0 + l15) * NGRP + (k0 >> 2) + l4 * 2;

  f32x4 acc[4][4] = {};
  int2 qA[4], qB[4];

  auto qload = [&](int2* q, int t) {
#pragma unroll
    for (int ni = 0; ni < 4; ++ni)
      q[ni] = *reinterpret_cast<const int2*>(qb + (size_t)ni * 16 * NGRP + t * 8);
  };
  auto step = [&](const int2* q, int t) {
    bf16x8 b[4];
#pragma unroll
    for (int ni = 0; ni < 4; ++ni) {
      union { unsigned long long u[2]; bf16x8 v; } c;
      c.u[0] = tbl[q[ni].x & 255];
      c.u[1] = tbl[q[ni].y & 255];
      b[ni] = c.v;
    }
#pragma unroll
    for (int mi = 0; mi < 4; ++mi) {
      bf16x8 a = *reinterpret_cast<const bf16x8*>(
          ab + (size_t)mi * 16 * INF + t * 32);
#pragma unroll
      for (int ni = 0; ni < 4; ++ni)
        acc[mi][ni] = __builtin_amdgcn_mfma_f32_16x16x32_bf16(
            a, b[ni], acc[mi][ni], 0, 0, 0);
    }
  };

  // ---- k-loop, register double-buffered Qidxs (prefetch distance ~1.5 steps)
  qload(qA, 0);
  for (int t = 0; t < NSTEP; t += 2) {
    qload(qB, t + 1);
    step(qA, t);
    if (t + 2 < NSTEP) qload(qA, t + 2);
    step(qB, t + 1);
  }

  // ---- write this wave's partial tile to LDS
  {
    float* rw = &red[wave][0];
#pragma unroll
    for (int mi = 0; mi < 4; ++mi)
#pragma unroll
      for (int ni = 0; ni < 4; ++ni)
#pragma unroll
        for (int r = 0; r < 4; ++r)
          rw[(mi * 16 + l4 * 4 + r) * RP + ni * 16 + l15] = acc[mi][ni][r];
  }
  __syncthreads();

  // ---- reduce 8 partials, store coalesced float4 (exclusive ownership)
  const int qn = tid & 15;        // n-quad
  const int mr = tid >> 4;        // 0..31
#pragma unroll
  for (int mm = mr; mm < BM; mm += 32) {
    float4 s = make_float4(0.f, 0.f, 0.f, 0.f);
#pragma unroll
    for (int w = 0; w < 8; ++w) {
      float4 p = *reinterpret_cast<const float4*>(&red[w][mm * RP + qn * 4]);
      s.x += p.x; s.y += p.y; s.z += p.z; s.w += p.w;
    }
    *reinterpret_cast<float4*>(
        &out[(size_t)(m0 + mm) * MOUT + n0 + qn * 4]) = s;
  }
}

extern "C" void kernel_launch(void* const* d_in, const int* in_sizes, int n_in,
                              void* d_out, int out_size, void* d_ws, size_t ws_size,
                              hipStream_t stream) {
  const float* inp = (const float*)d_in[0];
  const float* sw  = (const float*)d_in[1];
  const float* qs  = (const float*)d_in[2];
  const int*   qi  = (const int*)d_in[3];
  float* out = (float*)d_out;
  unsigned short* xs = (unsigned short*)d_ws;   // 256*4096 bf16 = 2 MB scratch

  prep_kernel<<<(BATCH * INF / 4) / 256, 256, 0, stream>>>(inp, sw, qs, xs);

  constexpr int GRID = (BATCH / BM) * (MOUT / BN);   // 4 * 64 = 256
  gemm_kernel<<<GRID, 512, 0, stream>>>(xs, qi, out);
}